// Round 1
// baseline (206.822 us; speedup 1.0000x reference)
//
#include <hip/hip_runtime.h>
#include <hip/hip_bf16.h>
#include <stdint.h>

#define AS1 __attribute__((address_space(1)))
#define AS3 __attribute__((address_space(3)))

typedef __attribute__((ext_vector_type(8))) short short8;
typedef __attribute__((ext_vector_type(4))) float f32x4;
typedef __attribute__((ext_vector_type(4))) int i32x4;

__device__ __forceinline__ unsigned short f2bf(float f) {
  return __builtin_bit_cast(unsigned short, __float2bfloat16(f));
}

// ---------------------------------------------------------------------------
// Kernel 1 (fused quant prep): one block per matrix row.
// Blocks [0, wrows): FWHT-128 on W row (fp32, in-register) -> row absmax ->
//   i8 quantize -> Wq, s_w[row].
// Blocks [wrows, ...): x row absmax -> i8 quantize -> Xq, s_x[row].
// 256 thr x 16 elems = 4096 elems/row. Exact per-row absmax => no clipping;
// error is pure rounding (~0.9% rms per element).
// ---------------------------------------------------------------------------
__global__ __launch_bounds__(256) void quant_prep(const float* __restrict__ W,
                                                  signed char* __restrict__ Wq,
                                                  float* __restrict__ sw,
                                                  const float* __restrict__ x,
                                                  signed char* __restrict__ Xq,
                                                  float* __restrict__ sx,
                                                  int wrows, int Kd) {
  __shared__ float red[4];
  const int bid = blockIdx.x;
  const int tid = threadIdx.x;
  const bool isW = bid < wrows;
  const int row = isW ? bid : bid - wrows;
  const float* src = (isW ? W : x) + (size_t)row * Kd + tid * 16;

  float v[16];
  {
    float4 f0 = ((const float4*)src)[0];
    float4 f1 = ((const float4*)src)[1];
    float4 f2 = ((const float4*)src)[2];
    float4 f3 = ((const float4*)src)[3];
    v[0] = f0.x; v[1] = f0.y; v[2] = f0.z; v[3] = f0.w;
    v[4] = f1.x; v[5] = f1.y; v[6] = f1.z; v[7] = f1.w;
    v[8] = f2.x; v[9] = f2.y; v[10] = f2.z; v[11] = f2.w;
    v[12] = f3.x; v[13] = f3.y; v[14] = f3.z; v[15] = f3.w;
  }

  if (isW) {
    // FWHT-128: thread holds 16 contiguous elems (bits 0..3); a 128-segment
    // spans 8 threads (bits 4..6 = tid&7), all within one wave.
#pragma unroll
    for (int m = 1; m <= 8; m <<= 1) {
#pragma unroll
      for (int j = 0; j < 16; ++j) {
        if ((j & m) == 0) {
          float lo = v[j], hi = v[j + m];
          v[j] = lo + hi;
          v[j + m] = lo - hi;
        }
      }
    }
    const int g = tid & 7;
#pragma unroll
    for (int m = 1; m <= 4; m <<= 1) {
#pragma unroll
      for (int j = 0; j < 16; ++j) {
        float p = __shfl_xor(v[j], m, 64);
        v[j] = (g & m) ? (p - v[j]) : (v[j] + p);
      }
    }
    const float s = 0.08838834764831845f; // 1/sqrt(128)
#pragma unroll
    for (int j = 0; j < 16; ++j) v[j] *= s;
  }

  // row absmax: wave reduce then block reduce (4 waves)
  float am = 0.f;
#pragma unroll
  for (int j = 0; j < 16; ++j) am = fmaxf(am, fabsf(v[j]));
#pragma unroll
  for (int m = 1; m < 64; m <<= 1) am = fmaxf(am, __shfl_xor(am, m, 64));
  if ((tid & 63) == 0) red[tid >> 6] = am;
  __syncthreads();
  am = fmaxf(fmaxf(red[0], red[1]), fmaxf(red[2], red[3]));

  const float inv = (am > 1e-30f) ? (127.0f / am) : 0.f;
  union { uint4 u; signed char c[16]; } pk;
#pragma unroll
  for (int j = 0; j < 16; ++j) {
    float q = __builtin_rintf(v[j] * inv);
    q = fminf(127.f, fmaxf(-127.f, q));
    pk.c[j] = (signed char)(int)q;
  }
  signed char* dst = (isW ? Wq : Xq) + (size_t)row * Kd + tid * 16;
  *(uint4*)dst = pk.u;
  if (tid == 0) (isW ? sw : sx)[row] = am / 127.0f;
}

// ---------------------------------------------------------------------------
__device__ __forceinline__ void gload16(const void* g, void* l) {
  __builtin_amdgcn_global_load_lds((const AS1 unsigned int*)g,
                                   (AS3 unsigned int*)l, 16, 0, 0);
}

// ---------------------------------------------------------------------------
// Kernel 2: i8 GEMM, co-residency build (2 blocks/CU).
//
// vs the previous 256x256/128KiB-LDS/256-reg version (1 block/CU, MfmaUtil
// 43%, Occupancy 20%): tile 128x256, per-wave output 64x64 (acc 64 regs,
// __launch_bounds__(512,4) caps total regs at 128 => 4 waves/SIMD), LDS =
// 3-slot ring of 24 KiB K-tiles (BK=64) = 72 KiB => two independent blocks
// co-reside per CU. Barrier stalls and the fp32 epilogue of one block hide
// under the other block's MFMAs.
//
// Per phase (= one BK=64 K-tile): vmcnt(3)+barrier publishes tile t (its 3
// loads were issued 2 phases ago; ring keeps 3-6 loads in flight, never
// drains to 0 in the loop), 8x ds_read_b128 (same XOR-swizzle as before,
// 0 bank conflicts), stage tile t+2 (3x global_load_lds dwordx4),
// lgkmcnt(0), setprio(1) + 16x mfma_i32_16x16x64_i8.
// Slot restage hazard is one-barrier-safe: slot read in phase t is drained
// by that phase's lgkmcnt(0) (before MFMA), restaged only after barrier t+1.
// Dequant epilogue: out = sx[m]*sw[n]*acc + b[n]  (integer accum is exact).
// ---------------------------------------------------------------------------
#define BM2 128
#define BN2 256
#define SLOTSZ 24576 // A plane 8192 B (128 rows x 64) + B plane 16384 B (256 rows x 64)

__global__ __launch_bounds__(512, 4) void gemm_i8_2blk(const signed char* __restrict__ Xq,
                                                       const signed char* __restrict__ Wq,
                                                       const float* __restrict__ sx,
                                                       const float* __restrict__ sw,
                                                       const float* __restrict__ bias,
                                                       float* __restrict__ out,
                                                       int M, int N, int K) {
  __shared__ __align__(16) char lds[3 * SLOTSZ];

  const int tid = threadIdx.x;
  const int lane = tid & 63;
  const int wid = tid >> 6; // 0..7
  const int wm = wid >> 2;  // 0..1  (64-row strip)
  const int wn = wid & 3;   // 0..3  (64-col strip)

  // XCD bijective swizzle (gridDim.x = 1024, multiple of 8)
  const int nwg = gridDim.x;
  const int cpx = nwg >> 3;
  const int swzb = (blockIdx.x & 7) * cpx + (blockIdx.x >> 3);
  const int nbn = N / BN2;
  const int m0 = (swzb / nbn) * BM2;
  const int n0 = (swzb % nbn) * BN2;
  const size_t Kb = (size_t)K; // 1 byte/elem

  // ---- stage source pointers: pre-swizzled global (rule #21) ----
  // LDS dest is linear (global_load_lds requirement); the XOR involution is
  // applied to the plane-relative dest offset to derive the global source.
  const int dA = tid * 16;         // A plane-relative [0, 8192)
  const int dB0 = tid * 16;        // B plane-relative [0, 8192)
  const int dB1 = tid * 16 + 8192; // B plane-relative [8192, 16384)
  const char* srcA;
  const char* srcB0;
  const char* srcB1;
  {
    int l = dA ^ (((dA >> 7) & 3) << 4);
    srcA = (const char*)Xq + (size_t)(m0 + (l >> 6)) * Kb + (l & 63);
    l = dB0 ^ (((dB0 >> 7) & 3) << 4);
    srcB0 = (const char*)Wq + (size_t)(n0 + (l >> 6)) * Kb + (l & 63);
    l = dB1 ^ (((dB1 >> 7) & 3) << 4);
    srcB1 = (const char*)Wq + (size_t)(n0 + (l >> 6)) * Kb + (l & 63);
  }

  // ---- swizzled in-plane ds_read offsets (same involution) ----
  const int q = lane >> 4;  // k-chunk 0..3 (16 B each = 16 i8)
  const int fr = lane & 15; // frag row
  int oA[4], oB[4];
#pragma unroll
  for (int mi = 0; mi < 4; ++mi) {
    int row = wm * 64 + mi * 16 + fr; // 0..127
    int byt = row * 64 + q * 16;
    oA[mi] = byt ^ (((byt >> 7) & 3) << 4);
  }
#pragma unroll
  for (int ni = 0; ni < 4; ++ni) {
    int row = wn * 64 + ni * 16 + fr; // 0..255
    int byt = row * 64 + q * 16;
    oB[ni] = 8192 + (byt ^ (((byt >> 7) & 3) << 4)); // +8192 = B plane base
  }

  i32x4 acc[4][4];
#pragma unroll
  for (int i = 0; i < 4; ++i)
#pragma unroll
    for (int j = 0; j < 4; ++j) acc[i][j] = (i32x4){0, 0, 0, 0};

#define STAGE3(sl_, ko_)                                                     \
  do {                                                                       \
    gload16(srcA + (ko_), (sl_) + dA);                                       \
    gload16(srcB0 + (ko_), (sl_) + 8192 + dB0);                              \
    gload16(srcB1 + (ko_), (sl_) + 8192 + dB1);                              \
  } while (0)

  // ---- prologue: tile0 -> slot0, tile1 -> slot1; publish tile0 ----
  STAGE3(lds, 0);
  STAGE3(lds + SLOTSZ, 64);
  asm volatile("s_waitcnt vmcnt(3)" ::: "memory"); // tile0 landed (tile1 in flight)
  __builtin_amdgcn_s_barrier();
  asm volatile("" ::: "memory");

  char* s0 = lds;              // holds tile t   (published)
  char* s1 = lds + SLOTSZ;     // holds tile t+1 (in flight / landing)
  char* s2 = lds + 2 * SLOTSZ; // dead (tile t-1) -> stage target for t+2
  int koff = 128;              // byte offset along K of tile t+2
  const int NT = K >> 6;       // 64

  for (int t = 0; t < NT; ++t) {
    i32x4 av[4], bv[4];
#pragma unroll
    for (int mi = 0; mi < 4; ++mi) av[mi] = *(const i32x4*)(s0 + oA[mi]);
#pragma unroll
    for (int ni = 0; ni < 4; ++ni) bv[ni] = *(const i32x4*)(s0 + oB[ni]);
    STAGE3(s2, koff); // issue tile t+2 (lands over the next 2 phases)
    koff += 64;
    if (koff >= K) koff -= K; // ring wrap: tail phases harmlessly re-stage t0/t1
    asm volatile("s_waitcnt lgkmcnt(0)" ::: "memory");
    __builtin_amdgcn_sched_barrier(0);
    __builtin_amdgcn_s_setprio(1);
#pragma unroll
    for (int mi = 0; mi < 4; ++mi)
#pragma unroll
      for (int ni = 0; ni < 4; ++ni)
        acc[mi][ni] = __builtin_amdgcn_mfma_i32_16x16x64_i8(av[mi], bv[ni],
                                                            acc[mi][ni], 0, 0, 0);
    __builtin_amdgcn_s_setprio(0);
    __builtin_amdgcn_sched_barrier(0);

    // rotate ring and publish tile t+1: its 3 loads were issued in phase t-1;
    // outstanding here = {t+1:3, t+2:3} -> vmcnt(3) drains exactly t+1.
    char* tp = s0; s0 = s1; s1 = s2; s2 = tp;
    asm volatile("s_waitcnt vmcnt(3)" ::: "memory");
    __builtin_amdgcn_s_barrier();
    asm volatile("" ::: "memory");
  }
  asm volatile("s_waitcnt vmcnt(0)" ::: "memory"); // drain wrapped ring stages

  // ---- epilogue: C/D col=lane&15, row=(lane>>4)*4+r (dtype-independent);
  // dequant out = sx[row]*sw[col]*acc + b[col], fp32 store.
  const int orow = m0 + wm * 64;
  const int ocol = n0 + wn * 64;
  const int rsub = q << 2;
#pragma unroll
  for (int ni = 0; ni < 4; ++ni) {
    const int col = ocol + ni * 16 + fr;
    const float swc = sw[col];
    const float bc = bias[col];
#pragma unroll
    for (int mi = 0; mi < 4; ++mi) {
      const int rbase = orow + mi * 16 + rsub;
#pragma unroll
      for (int r = 0; r < 4; ++r) {
        const int row = rbase + r;
        out[(size_t)row * N + col] =
            (float)acc[mi][ni][r] * (sx[row] * swc) + bc;
      }
    }
  }
#undef STAGE3
}

// ---------------------------------------------------------------------------
// Fallback (small workspace): bf16 path — standalone FWHT + 128^2 GEMM.
// ---------------------------------------------------------------------------
__global__ __launch_bounds__(256) void fwht_only(const float* __restrict__ W,
                                                 unsigned short* __restrict__ Wp,
                                                 int total_vec) {
  int t = blockIdx.x * blockDim.x + threadIdx.x;
  if (t >= total_vec) return;
  float4 r0 = ((const float4*)W)[2 * t];
  float4 r1 = ((const float4*)W)[2 * t + 1];
  float v[8] = {r0.x, r0.y, r0.z, r0.w, r1.x, r1.y, r1.z, r1.w};
#pragma unroll
  for (int m = 1; m <= 4; m <<= 1) {
#pragma unroll
    for (int j = 0; j < 8; ++j) {
      if ((j & m) == 0) {
        float lo = v[j], hi = v[j + m];
        v[j] = lo + hi;
        v[j + m] = lo - hi;
      }
    }
  }
  const int g = t & 15;
#pragma unroll
  for (int m = 1; m <= 8; m <<= 1) {
#pragma unroll
    for (int j = 0; j < 8; ++j) {
      float p = __shfl_xor(v[j], m, 64);
      v[j] = (g & m) ? (p - v[j]) : (v[j] + p);
    }
  }
  const float s = 0.08838834764831845f;
  uint4 outv;
  unsigned short* ou = (unsigned short*)&outv;
#pragma unroll
  for (int j = 0; j < 8; ++j) ou[j] = f2bf(v[j] * s);
  ((uint4*)Wp)[t] = outv;
}

__global__ __launch_bounds__(256) void gemm128_a32(const float* __restrict__ X,
                                                   const unsigned short* __restrict__ Wp,
                                                   const float* __restrict__ bias,
                                                   float* __restrict__ out,
                                                   int M, int N, int K) {
  __shared__ __align__(16) unsigned short lA[128 * 32];
  __shared__ __align__(16) unsigned short lB[128 * 32];
  const int tid = threadIdx.x;
  const int lane = tid & 63;
  const int wid = tid >> 6;
  const int wr = wid >> 1, wc = wid & 1;
  const int nbn = N / 128;
  const int bm = blockIdx.x / nbn, bn = blockIdx.x % nbn;
  const int m0 = bm * 128, n0 = bn * 128;
  f32x4 acc[4][4];
#pragma unroll
  for (int i = 0; i < 4; ++i)
#pragma unroll
    for (int j = 0; j < 4; ++j) acc[i][j] = (f32x4){0.f, 0.f, 0.f, 0.f};
  const size_t Kb = (size_t)K * 2;
  const int off0 = tid * 16, off1 = off0 + 4096;
  const int r0 = off0 >> 6, c0 = off0 & 63;
  const int r1 = off1 >> 6, c1 = off1 & 63;
  const char* Bg0 = (const char*)Wp + (size_t)(n0 + r0) * Kb + c0;
  const char* Bg1 = (const char*)Wp + (size_t)(n0 + r1) * Kb + c1;
  char* lB0 = (char*)lB + off0;
  char* lB1 = (char*)lB + off1;
  const int arow = tid >> 1;
  const int acol = (tid & 1) * 16;
  const float* Af = X + (size_t)(m0 + arow) * K + acol;
  unsigned short* lAw = &lA[arow * 32 + acol];
  const int fr = lane & 15;
  const int kc = (lane >> 4) << 3;
  const unsigned short* pA = &lA[(wr * 64 + fr) * 32 + kc];
  const unsigned short* pB = &lB[(wc * 64 + fr) * 32 + kc];
  for (int k0 = 0; k0 < K; k0 += 32) {
    const int kb = k0 << 1;
    gload16(Bg0 + kb, lB0);
    gload16(Bg1 + kb, lB1);
    const float* src = Af + k0;
    float4 f0 = *(const float4*)(src + 0);
    float4 f1 = *(const float4*)(src + 4);
    float4 f2 = *(const float4*)(src + 8);
    float4 f3 = *(const float4*)(src + 12);
    union { uint4 u[2]; unsigned short s[16]; } pk;
    float vv[16] = {f0.x, f0.y, f0.z, f0.w, f1.x, f1.y, f1.z, f1.w,
                    f2.x, f2.y, f2.z, f2.w, f3.x, f3.y, f3.z, f3.w};
#pragma unroll
    for (int j = 0; j < 16; ++j) pk.s[j] = f2bf(vv[j]);
    ((uint4*)lAw)[0] = pk.u[0];
    ((uint4*)(lAw + 8))[0] = pk.u[1];
    __syncthreads();
    short8 af[4], bfr[4];
#pragma unroll
    for (int mi = 0; mi < 4; ++mi) af[mi] = *(const short8*)(pA + mi * 16 * 32);
#pragma unroll
    for (int ni = 0; ni < 4; ++ni) bfr[ni] = *(const short8*)(pB + ni * 16 * 32);
#pragma unroll
    for (int mi = 0; mi < 4; ++mi)
#pragma unroll
      for (int ni = 0; ni < 4; ++ni)
        acc[mi][ni] = __builtin_amdgcn_mfma_f32_16x16x32_bf16(af[mi], bfr[ni],
                                                              acc[mi][ni], 0, 0, 0);
    __syncthreads();
  }
  const int orow0 = m0 + wr * 64;
  const int ocol0 = n0 + wc * 64;
  const int rsub = (lane >> 4) << 2;
#pragma unroll
  for (int ni = 0; ni < 4; ++ni) {
    const int col = ocol0 + ni * 16 + fr;
    const float bc = bias[col];
#pragma unroll
    for (int mi = 0; mi < 4; ++mi)
#pragma unroll
      for (int r = 0; r < 4; ++r)
        out[(size_t)(orow0 + mi * 16 + rsub + r) * N + col] = acc[mi][ni][r] + bc;
  }
}

// ---------------------------------------------------------------------------
extern "C" void kernel_launch(void* const* d_in, const int* in_sizes, int n_in,
                              void* d_out, int out_size, void* d_ws, size_t ws_size,
                              hipStream_t stream) {
  const float* x = (const float*)d_in[0];
  const float* W = (const float*)d_in[1];
  const float* b = (const float*)d_in[2];
  float* out = (float*)d_out;

  const int O = in_sizes[2];     // 4096
  const int K = in_sizes[1] / O; // 4096
  const int M = in_sizes[0] / K; // 8192

  const size_t wqB = (size_t)O * K;       // i8 W'
  const size_t xqB = (size_t)M * K;       // i8 x
  const size_t need = wqB + xqB + (size_t)(O + M) * 4 + 256;

  if (ws_size >= need) {
    signed char* Wq = (signed char*)d_ws;
    signed char* Xq = (signed char*)d_ws + wqB;
    float* sw = (float*)((char*)d_ws + wqB + xqB);
    float* sx = sw + O;
    quant_prep<<<O + M, 256, 0, stream>>>(W, Wq, sw, x, Xq, sx, O, K);
    dim3 grid((M / BM2) * (O / BN2)); // 64*16 = 1024, %8 == 0
    gemm_i8_2blk<<<grid, 512, 0, stream>>>(Xq, Wq, sx, sw, b, out, M, O, K);
  } else {
    unsigned short* Wp = (unsigned short*)d_ws;
    const int wvec = (O * K) / 8;
    fwht_only<<<(wvec + 255) / 256, 256, 0, stream>>>(W, Wp, wvec);
    dim3 grid((M / 128) * (O / 128));
    gemm128_a32<<<grid, 256, 0, stream>>>(x, Wp, b, out, M, O, K);
  }
}